// Round 14
// baseline (290.803 us; speedup 1.0000x reference)
//
#include <hip/hip_runtime.h>
#include <hip/hip_bf16.h>

#define NGRAPH 4096
#define TPW 8   // tiles (16 rows each) per wave

typedef __attribute__((ext_vector_type(8))) short s16x8;
typedef __attribute__((ext_vector_type(4))) float f32x4;
typedef unsigned int u32;

__device__ inline short f2bf(float f) {
  unsigned u = __float_as_uint(f);
  unsigned r = u + 0x7fffu + ((u >> 16) & 1u);
  return (short)(r >> 16);
}

// Prepack W1 (256x128 fp32, row-major) into bf16 MFMA B-fragment order.
// Fragment f = kt*8 + ct (kt,ct in 0..7). Lane l supplies B[k][c] for
// k = kt*32 + (l>>4)*8 + e (e=0..7), c = ct*16 + (l&15).
__global__ void prepack_w1(const float* __restrict__ W1, s16x8* __restrict__ w1p) {
  int t = blockIdx.x * 256 + threadIdx.x;   // 4096 threads total
  int f = t >> 6, l = t & 63;
  int kt = f >> 3, ct = f & 7;
  int k0 = kt * 32 + ((l >> 4) * 8);
  int c  = ct * 16 + (l & 15);
  s16x8 v;
  #pragma unroll
  for (int e = 0; e < 8; ++e) v[e] = f2bf(W1[(k0 + e) * 128 + c]);
  w1p[f * 64 + l] = v;
}

__device__ inline long long getb(const void* b, int i, int is64) {
  if (is64) return ((const long long*)b)[i];
  return (long long)((const int*)b)[i];
}

__device__ inline int lowb(const void* b, int n, long long v, int is64) {
  int lo = 0, hi = n;
  while (lo < hi) {
    int mid = (lo + hi) >> 1;
    if (getb(b, mid, is64) < v) lo = mid + 1; else hi = mid;
  }
  return lo;
}

__device__ inline int batch_is64(const void* batch, int N) {
  // int64 vs int32 materialization probe: an odd 32-bit word index has a zero
  // high word under int64 (values < 2^31), a near-max sorted id under int32.
  int probe = ((N & 1) == 0) ? (N - 1) : (N - 2);
  return (((const int*)batch)[probe] == 0) ? 1 : 0;
}

// One-time: offs[g] = lower_bound(batch, g).
__global__ void seg_offsets(const void* __restrict__ batch, int* __restrict__ offs, int N) {
  int g = blockIdx.x * 256 + threadIdx.x;
  const int is64 = batch_is64(batch, N);
  if (g <= NGRAPH) offs[g] = lowb(batch, N, (long long)g, is64);
}

__device__ inline float fast_tanh(float v) {
  v = fminf(fmaxf(v, -15.f), 15.f);
  float e = __expf(2.f * v);
  return __fdividef(e - 1.f, e + 1.f);
}

// WAVESTREAM kernel: each WAVE is a fully independent pipeline (no barriers
// after the one-time W1 LDS stage). Wave owns TPW consecutive 16-row tiles,
// FULL 128 hidden cols (no colhalf split -> no cross-wave score dependency).
// Depth-2 register pipeline: issue tile j+1's 16 global dwordx4 loads, then
// compute tile j -- the whole compute phase (~1+ us) hides HBM latency, and
// the W1 inner loop reads LDS (lgkmcnt), never polluting the vmcnt order.
// Scores: per-lane partial over 8 ct-frags -> shfl butterfly over l15 ->
// row score gathered per-lane via one bpermute -> myE = exp(score) (bounded,
// no max needed). Pooling: tile staged reg->LDS (b128, swizzled, conflict-
// free), each lane owns 4 consecutive cols, per-segment row loop with one
// bpermute per row for the weight; atomicAdd joins (buffers zeroed per call).
__global__ __launch_bounds__(256, 1)
void gate_pool(const float* __restrict__ x, const int* __restrict__ offs,
               const float* __restrict__ b1, const float* __restrict__ W2,
               const float* __restrict__ b2p, const s16x8* __restrict__ w1p,
               float* __restrict__ pooled, float* __restrict__ expout,
               float* __restrict__ segsum, int N, int ntiles)
{
  __shared__ __align__(16) s16x8 w1l[4096];          // 64 KB: all B-fragments
  __shared__ __align__(16) char pbufs[4][16 * 1024]; // 16 KB pool buf per wave

  const int tid = threadIdx.x;
  const int w = tid >> 6, l = tid & 63;
  const int l15 = l & 15, lg = l >> 4;

  // one-time cooperative stage of W1 fragments into LDS
  {
    const uint4* s = (const uint4*)w1p;
    uint4* d = (uint4*)w1l;
    #pragma unroll
    for (int i = 0; i < 16; ++i) d[i * 256 + tid] = s[i * 256 + tid];
  }

  float b1v[8], w2v[8];
  #pragma unroll
  for (int ct = 0; ct < 8; ++ct) {
    int c = ct * 16 + l15;
    b1v[ct] = b1[c];
    w2v[ct] = W2[c];
  }
  const float b2s = b2p[0];
  __syncthreads();               // the only block barrier in the kernel

  const int gwave = blockIdx.x * 4 + w;
  const int tbase = gwave * TPW;
  if (tbase >= ntiles) return;

  char* pb = pbufs[w];
  const int ck0 = (l15 >> 1) * 32 + lg * 8 + (l15 & 1) * 4; // lane's 4 cols
  const int ckc = ck0 >> 2;                                  // its 16B chunk

#define ISSUE(XB, TT) do {                                                   \
    int row_ = (TT) * 16 + l15; if (row_ > N - 1) row_ = N - 1;              \
    const float* xp_ = x + (size_t)row_ * 256 + lg * 8;                      \
    _Pragma("unroll")                                                        \
    for (int kt_ = 0; kt_ < 8; ++kt_) {                                      \
      XB[2*kt_]     = *(const float4*)(xp_ + kt_ * 32);                      \
      XB[2*kt_ + 1] = *(const float4*)(xp_ + kt_ * 32 + 4);                  \
    } } while (0)

#define PROCESS(XB, TT) do {                                                 \
    const int n0_ = (TT) * 16;                                               \
    if (n0_ < N) {                                                           \
      f32x4 ac0={0.f,0.f,0.f,0.f}, ac1={0.f,0.f,0.f,0.f};                    \
      f32x4 ac2={0.f,0.f,0.f,0.f}, ac3={0.f,0.f,0.f,0.f};                    \
      f32x4 ac4={0.f,0.f,0.f,0.f}, ac5={0.f,0.f,0.f,0.f};                    \
      f32x4 ac6={0.f,0.f,0.f,0.f}, ac7={0.f,0.f,0.f,0.f};                    \
      _Pragma("unroll")                                                      \
      for (int kt_ = 0; kt_ < 8; ++kt_) {                                    \
        s16x8 a_;                                                            \
        a_[0]=f2bf(XB[2*kt_].x);   a_[1]=f2bf(XB[2*kt_].y);                  \
        a_[2]=f2bf(XB[2*kt_].z);   a_[3]=f2bf(XB[2*kt_].w);                  \
        a_[4]=f2bf(XB[2*kt_+1].x); a_[5]=f2bf(XB[2*kt_+1].y);                \
        a_[6]=f2bf(XB[2*kt_+1].z); a_[7]=f2bf(XB[2*kt_+1].w);                \
        const s16x8* wb_ = &w1l[kt_ * 512 + l];                              \
        ac0 = __builtin_amdgcn_mfma_f32_16x16x32_bf16(a_, wb_[0],   ac0,0,0,0); \
        ac1 = __builtin_amdgcn_mfma_f32_16x16x32_bf16(a_, wb_[64],  ac1,0,0,0); \
        ac2 = __builtin_amdgcn_mfma_f32_16x16x32_bf16(a_, wb_[128], ac2,0,0,0); \
        ac3 = __builtin_amdgcn_mfma_f32_16x16x32_bf16(a_, wb_[192], ac3,0,0,0); \
        ac4 = __builtin_amdgcn_mfma_f32_16x16x32_bf16(a_, wb_[256], ac4,0,0,0); \
        ac5 = __builtin_amdgcn_mfma_f32_16x16x32_bf16(a_, wb_[320], ac5,0,0,0); \
        ac6 = __builtin_amdgcn_mfma_f32_16x16x32_bf16(a_, wb_[384], ac6,0,0,0); \
        ac7 = __builtin_amdgcn_mfma_f32_16x16x32_bf16(a_, wb_[448], ac7,0,0,0); \
      }                                                                      \
      /* D layout: node = 4*lg + r_, col = ct*16 + l15 */                    \
      float part[4];                                                         \
      _Pragma("unroll")                                                      \
      for (int r_ = 0; r_ < 4; ++r_) {                                       \
        part[r_] = b2s                                                       \
          + fast_tanh(ac0[r_]+b1v[0])*w2v[0] + fast_tanh(ac1[r_]+b1v[1])*w2v[1] \
          + fast_tanh(ac2[r_]+b1v[2])*w2v[2] + fast_tanh(ac3[r_]+b1v[3])*w2v[3] \
          + fast_tanh(ac4[r_]+b1v[4])*w2v[4] + fast_tanh(ac5[r_]+b1v[5])*w2v[5] \
          + fast_tanh(ac6[r_]+b1v[6])*w2v[6] + fast_tanh(ac7[r_]+b1v[7])*w2v[7]; \
      }                                                                      \
      _Pragma("unroll")                                                      \
      for (int m_ = 1; m_ <= 8; m_ <<= 1) {                                  \
        part[0] += __shfl_xor(part[0], m_, 64);                              \
        part[1] += __shfl_xor(part[1], m_, 64);                              \
        part[2] += __shfl_xor(part[2], m_, 64);                              \
        part[3] += __shfl_xor(part[3], m_, 64);                              \
      }                                                                      \
      /* lane's own-row score: row l15 = 4*(l15>>2) + (l15&3) */             \
      float v_ = part[0];                                                    \
      v_ = ((l15 & 3) == 1) ? part[1] : v_;                                  \
      v_ = ((l15 & 3) == 2) ? part[2] : v_;                                  \
      v_ = ((l15 & 3) == 3) ? part[3] : v_;                                  \
      const float myE = __expf(__shfl(v_, l15 + ((l15 >> 2) << 4), 64));     \
      if (l < 16 && n0_ + l < N) expout[n0_ + l] = myE;                      \
      /* stage tile regs -> pool buffer (swizzled b128, conflict-free) */    \
      _Pragma("unroll")                                                      \
      for (int kt_ = 0; kt_ < 8; ++kt_) {                                    \
        int cA_ = kt_ * 8 + lg * 2;                                          \
        *(float4*)(pb + l15*1024 + (((cA_    ) ^ (l15 & 7)) << 4)) = XB[2*kt_];   \
        *(float4*)(pb + l15*1024 + (((cA_ + 1) ^ (l15 & 7)) << 4)) = XB[2*kt_+1]; \
      }                                                                      \
      /* per-segment pooling over this tile's rows */                        \
      const int nmax_ = min(16, N - n0_);                                    \
      int g_;                                                                \
      { int lo_ = 0, hi_ = NGRAPH - 1;                                       \
        while (lo_ < hi_) { int mid_ = (lo_ + hi_) >> 1;                     \
          if (offs[mid_ + 1] <= n0_) lo_ = mid_ + 1; else hi_ = mid_; }      \
        g_ = lo_; }                                                          \
      int r_ = 0; int nb_ = offs[g_ + 1];                                    \
      while (r_ < nmax_) {                                                   \
        const int rend_ = min(nb_ - n0_, nmax_);                             \
        float wm_ = (l15 >= r_ && l15 < rend_) ? myE : 0.f;                  \
        float p0_ = 0.f, p1_ = 0.f, p2_ = 0.f, p3_ = 0.f;                    \
        for (; r_ < rend_; ++r_) {                                           \
          float wr_ = __shfl(myE, r_, 64);                                   \
          float4 xv_ = *(const float4*)(pb + r_*1024 + ((ckc ^ (r_ & 7)) << 4)); \
          p0_ += wr_ * xv_.x; p1_ += wr_ * xv_.y;                            \
          p2_ += wr_ * xv_.z; p3_ += wr_ * xv_.w;                            \
        }                                                                    \
        float ss_ = wm_;                                                     \
        ss_ += __shfl_xor(ss_, 1, 64); ss_ += __shfl_xor(ss_, 2, 64);        \
        ss_ += __shfl_xor(ss_, 4, 64); ss_ += __shfl_xor(ss_, 8, 64);        \
        if (ss_ > 0.f) {                                                     \
          atomicAdd(&pooled[(size_t)g_ * 256 + ck0 + 0], p0_);               \
          atomicAdd(&pooled[(size_t)g_ * 256 + ck0 + 1], p1_);               \
          atomicAdd(&pooled[(size_t)g_ * 256 + ck0 + 2], p2_);               \
          atomicAdd(&pooled[(size_t)g_ * 256 + ck0 + 3], p3_);               \
          if (l == 0) atomicAdd(&segsum[g_], ss_);                           \
        }                                                                    \
        if (rend_ >= nmax_) break;                                           \
        ++g_; nb_ = offs[g_ + 1];                                            \
      }                                                                      \
    } } while (0)

  float4 xbA[16], xbB[16];
  ISSUE(xbA, tbase);
  #pragma unroll
  for (int p = 0; p < TPW / 2; ++p) {
    ISSUE(xbB, tbase + 2 * p + 1);
    PROCESS(xbA, tbase + 2 * p);
    if (2 * p + 2 < TPW) ISSUE(xbA, tbase + 2 * p + 2);
    PROCESS(xbB, tbase + 2 * p + 1);
  }
#undef ISSUE
#undef PROCESS
}

// Finalize: pooled /= segsum (0 for empty graphs), weights = exp/segsum[batch].
__global__ void finalize(float* __restrict__ pooled, float* __restrict__ wts,
                         const float* __restrict__ segsum,
                         const void* __restrict__ batch, int N)
{
  int f = blockIdx.x * 256 + threadIdx.x;
  if (f < NGRAPH * 256) {
    int g = f >> 8;
    float s = segsum[g];
    pooled[f] = (s > 0.f) ? pooled[f] / s : 0.f;
  } else {
    int n = f - NGRAPH * 256;
    if (n < N) {
      const int is64 = batch_is64(batch, N);
      int g = (int)getb(batch, n, is64);
      wts[n] = wts[n] / segsum[g];
    }
  }
}

extern "C" void kernel_launch(void* const* d_in, const int* in_sizes, int n_in,
                              void* d_out, int out_size, void* d_ws, size_t ws_size,
                              hipStream_t stream) {
  const float* x     = (const float*)d_in[0];
  const void*  batch = d_in[1];
  const float* W1    = (const float*)d_in[2];
  const float* b1    = (const float*)d_in[3];
  const float* W2    = (const float*)d_in[4];
  const float* b2    = (const float*)d_in[5];
  const int N = in_sizes[0] / 256;
  const int ntiles = (N + 15) / 16;
  const int nwaves = (ntiles + TPW - 1) / TPW;
  const int nblocks = (nwaves + 3) / 4;

  float* pooled = (float*)d_out;                          // 4096*256
  float* wout   = (float*)d_out + (size_t)NGRAPH * 256;   // N: exp(s), then weights
  s16x8* w1p    = (s16x8*)d_ws;                           // 64 KB
  int*   offs   = (int*)((char*)d_ws + 64 * 1024);        // 4097 * 4 B
  float* segsum = (float*)((char*)d_ws + 96 * 1024);      // 4096 * 4 B

  // Atomic accumulators must start at zero EVERY call (graph replays included).
  hipMemsetAsync(pooled, 0, (size_t)NGRAPH * 256 * sizeof(float), stream);
  hipMemsetAsync(segsum, 0, (size_t)NGRAPH * sizeof(float), stream);

  prepack_w1<<<16, 256, 0, stream>>>(W1, w1p);
  seg_offsets<<<17, 256, 0, stream>>>(batch, offs, N);
  gate_pool<<<nblocks, 256, 0, stream>>>(x, offs, b1, W2, b2, w1p,
                                         pooled, wout, segsum, N, ntiles);
  const int tot = NGRAPH * 256 + N;
  finalize<<<(tot + 255) / 256, 256, 0, stream>>>(pooled, wout, segsum, batch, N);
}

// Round 15
// 252.716 us; speedup vs baseline: 1.1507x; 1.1507x over previous
//
#include <hip/hip_runtime.h>
#include <hip/hip_bf16.h>

#define NGRAPH 4096
#define TPW 8   // tiles (16 rows each) per wave

typedef __attribute__((ext_vector_type(8))) short s16x8;
typedef __attribute__((ext_vector_type(4))) float f32x4;
typedef unsigned int u32;

__device__ inline short f2bf(float f) {
  unsigned u = __float_as_uint(f);
  unsigned r = u + 0x7fffu + ((u >> 16) & 1u);
  return (short)(r >> 16);
}

// Prepack W1 (256x128 fp32, row-major) into bf16 MFMA B-fragment order.
// Fragment f = kt*8 + ct (kt,ct in 0..7). Lane l supplies B[k][c] for
// k = kt*32 + (l>>4)*8 + e (e=0..7), c = ct*16 + (l&15).
__global__ void prepack_w1(const float* __restrict__ W1, s16x8* __restrict__ w1p) {
  int t = blockIdx.x * 256 + threadIdx.x;   // 4096 threads total
  int f = t >> 6, l = t & 63;
  int kt = f >> 3, ct = f & 7;
  int k0 = kt * 32 + ((l >> 4) * 8);
  int c  = ct * 16 + (l & 15);
  s16x8 v;
  #pragma unroll
  for (int e = 0; e < 8; ++e) v[e] = f2bf(W1[(k0 + e) * 128 + c]);
  w1p[f * 64 + l] = v;
}

__device__ inline long long getb(const void* b, int i, int is64) {
  if (is64) return ((const long long*)b)[i];
  return (long long)((const int*)b)[i];
}

__device__ inline int lowb(const void* b, int n, long long v, int is64) {
  int lo = 0, hi = n;
  while (lo < hi) {
    int mid = (lo + hi) >> 1;
    if (getb(b, mid, is64) < v) lo = mid + 1; else hi = mid;
  }
  return lo;
}

__device__ inline int batch_is64(const void* batch, int N) {
  // int64 vs int32 materialization probe: an odd 32-bit word index has a zero
  // high word under int64 (values < 2^31), a near-max sorted id under int32.
  int probe = ((N & 1) == 0) ? (N - 1) : (N - 2);
  return (((const int*)batch)[probe] == 0) ? 1 : 0;
}

// One-time: offs[g] = lower_bound(batch, g).
__global__ void seg_offsets(const void* __restrict__ batch, int* __restrict__ offs, int N) {
  int g = blockIdx.x * 256 + threadIdx.x;
  const int is64 = batch_is64(batch, N);
  if (g <= NGRAPH) offs[g] = lowb(batch, N, (long long)g, is64);
}

__device__ inline float fast_tanh(float v) {
  v = fminf(fmaxf(v, -15.f), 15.f);
  float e = __expf(2.f * v);
  return __fdividef(e - 1.f, e + 1.f);
}

#define REDUCE16(v) do {                        \
    v += __shfl_xor(v, 1, 64);                  \
    v += __shfl_xor(v, 2, 64);                  \
    v += __shfl_xor(v, 4, 64);                  \
    v += __shfl_xor(v, 8, 64); } while (0)

// WAVESTREAM v2: each WAVE is a fully independent depth-2 register pipeline
// over TPW 16-row tiles, full 128 hidden cols (no cross-wave deps, no
// barriers in the loop). W1 fragments live in LDS (64 KB, staged once per
// block) so the inner loop's only vmcnt traffic is the x stream -> the
// compiler's counted vmcnt keeps the next tile's 16 loads in flight across
// the whole compute phase. LDS = 64 KB -> 2 blocks/CU (8 waves/CU), fixing
// R14's 1-wave/SIMD starvation. Pooling is IN-REGISTER: all 16 lanes of an
// lg-group hold the SAME 64 columns (different rows), so a 4-step shfl_xor
// over l15 reduces rows per column -- no LDS pool buffer, no bank conflicts.
// Scores bounded (|s| <= ||W2||_1 + |b2| ~ 9) -> exp without max-subtraction.
// Cross-tile segment joins via atomicAdd (buffers zeroed every call).
__global__ __launch_bounds__(256, 2)
void gate_pool(const float* __restrict__ x, const int* __restrict__ offs,
               const float* __restrict__ b1, const float* __restrict__ W2,
               const float* __restrict__ b2p, const s16x8* __restrict__ w1p,
               float* __restrict__ pooled, float* __restrict__ expout,
               float* __restrict__ segsum, int N, int ntiles)
{
  __shared__ __align__(16) s16x8 w1l[4096];          // 64 KB: all B-fragments

  const int tid = threadIdx.x;
  const int w = tid >> 6, l = tid & 63;
  const int l15 = l & 15, lg = l >> 4;

  // one-time cooperative stage of W1 fragments into LDS
  {
    const uint4* s = (const uint4*)w1p;
    uint4* d = (uint4*)w1l;
    #pragma unroll
    for (int i = 0; i < 16; ++i) d[i * 256 + tid] = s[i * 256 + tid];
  }

  float b1v[8], w2v[8];
  #pragma unroll
  for (int ct = 0; ct < 8; ++ct) {
    int c = ct * 16 + l15;
    b1v[ct] = b1[c];
    w2v[ct] = W2[c];
  }
  const float b2s = b2p[0];
  __syncthreads();               // the only block barrier in the kernel

  const int gwave = blockIdx.x * 4 + w;
  const int tbase = gwave * TPW;
  if (tbase >= ntiles) return;

#define ISSUE(XB, TT) do {                                                   \
    int row_ = (TT) * 16 + l15; if (row_ > N - 1) row_ = N - 1;              \
    const float* xp_ = x + (size_t)row_ * 256 + lg * 8;                      \
    _Pragma("unroll")                                                        \
    for (int kt_ = 0; kt_ < 8; ++kt_) {                                      \
      XB[2*kt_]     = *(const float4*)(xp_ + kt_ * 32);                      \
      XB[2*kt_ + 1] = *(const float4*)(xp_ + kt_ * 32 + 4);                  \
    } } while (0)

#define PROCESS(XB, TT) do {                                                 \
    const int n0_ = (TT) * 16;                                               \
    if (n0_ < N) {                                                           \
      f32x4 ac0={0.f,0.f,0.f,0.f}, ac1={0.f,0.f,0.f,0.f};                    \
      f32x4 ac2={0.f,0.f,0.f,0.f}, ac3={0.f,0.f,0.f,0.f};                    \
      f32x4 ac4={0.f,0.f,0.f,0.f}, ac5={0.f,0.f,0.f,0.f};                    \
      f32x4 ac6={0.f,0.f,0.f,0.f}, ac7={0.f,0.f,0.f,0.f};                    \
      _Pragma("unroll")                                                      \
      for (int kt_ = 0; kt_ < 8; ++kt_) {                                    \
        s16x8 a_;                                                            \
        a_[0]=f2bf(XB[2*kt_].x);   a_[1]=f2bf(XB[2*kt_].y);                  \
        a_[2]=f2bf(XB[2*kt_].z);   a_[3]=f2bf(XB[2*kt_].w);                  \
        a_[4]=f2bf(XB[2*kt_+1].x); a_[5]=f2bf(XB[2*kt_+1].y);                \
        a_[6]=f2bf(XB[2*kt_+1].z); a_[7]=f2bf(XB[2*kt_+1].w);                \
        const s16x8* wb_ = &w1l[kt_ * 512 + l];                              \
        ac0 = __builtin_amdgcn_mfma_f32_16x16x32_bf16(a_, wb_[0],   ac0,0,0,0); \
        ac1 = __builtin_amdgcn_mfma_f32_16x16x32_bf16(a_, wb_[64],  ac1,0,0,0); \
        ac2 = __builtin_amdgcn_mfma_f32_16x16x32_bf16(a_, wb_[128], ac2,0,0,0); \
        ac3 = __builtin_amdgcn_mfma_f32_16x16x32_bf16(a_, wb_[192], ac3,0,0,0); \
        ac4 = __builtin_amdgcn_mfma_f32_16x16x32_bf16(a_, wb_[256], ac4,0,0,0); \
        ac5 = __builtin_amdgcn_mfma_f32_16x16x32_bf16(a_, wb_[320], ac5,0,0,0); \
        ac6 = __builtin_amdgcn_mfma_f32_16x16x32_bf16(a_, wb_[384], ac6,0,0,0); \
        ac7 = __builtin_amdgcn_mfma_f32_16x16x32_bf16(a_, wb_[448], ac7,0,0,0); \
      }                                                                      \
      /* D layout: node = 4*lg + r_, col = ct*16 + l15 */                    \
      float part[4];                                                         \
      _Pragma("unroll")                                                      \
      for (int r_ = 0; r_ < 4; ++r_) {                                       \
        part[r_] = b2s                                                       \
          + fast_tanh(ac0[r_]+b1v[0])*w2v[0] + fast_tanh(ac1[r_]+b1v[1])*w2v[1] \
          + fast_tanh(ac2[r_]+b1v[2])*w2v[2] + fast_tanh(ac3[r_]+b1v[3])*w2v[3] \
          + fast_tanh(ac4[r_]+b1v[4])*w2v[4] + fast_tanh(ac5[r_]+b1v[5])*w2v[5] \
          + fast_tanh(ac6[r_]+b1v[6])*w2v[6] + fast_tanh(ac7[r_]+b1v[7])*w2v[7]; \
      }                                                                      \
      _Pragma("unroll")                                                      \
      for (int m_ = 1; m_ <= 8; m_ <<= 1) {                                  \
        part[0] += __shfl_xor(part[0], m_, 64);                              \
        part[1] += __shfl_xor(part[1], m_, 64);                              \
        part[2] += __shfl_xor(part[2], m_, 64);                              \
        part[3] += __shfl_xor(part[3], m_, 64);                              \
      }                                                                      \
      /* lane's own-row score: node l15 lives at lane (l15>>2)*16 + *,      */ \
      /* reg (l15&3); gather via one shfl                                   */ \
      float v_ = part[0];                                                    \
      v_ = ((l15 & 3) == 1) ? part[1] : v_;                                  \
      v_ = ((l15 & 3) == 2) ? part[2] : v_;                                  \
      v_ = ((l15 & 3) == 3) ? part[3] : v_;                                  \
      const float myE = __expf(__shfl(v_, l15 + ((l15 >> 2) << 4), 64));     \
      if (l < 16 && n0_ + l < N) expout[n0_ + l] = myE;                      \
      /* in-register pooling: per segment, mask rows, shfl-reduce over l15 */ \
      const int nmax_ = min(16, N - n0_);                                    \
      int g_;                                                                \
      { int lo_ = 0, hi_ = NGRAPH - 1;                                       \
        while (lo_ < hi_) { int mid_ = (lo_ + hi_) >> 1;                     \
          if (offs[mid_ + 1] <= n0_) lo_ = mid_ + 1; else hi_ = mid_; }      \
        g_ = lo_; }                                                          \
      int r_ = 0; int nb_ = offs[g_ + 1];                                    \
      while (true) {                                                         \
        const int rend_ = min(nb_ - n0_, nmax_);                             \
        if (rend_ > r_) {                                                    \
          const float wm_ = (l15 >= r_ && l15 < rend_) ? myE : 0.f;          \
          float ss_ = wm_;                                                   \
          REDUCE16(ss_);                                                     \
          if (ss_ > 0.f) {                                                   \
            _Pragma("unroll")                                                \
            for (int i_ = 0; i_ < 16; ++i_) {                                \
              float tx_ = XB[i_].x * wm_, ty_ = XB[i_].y * wm_;              \
              float tz_ = XB[i_].z * wm_, tw_ = XB[i_].w * wm_;              \
              REDUCE16(tx_); REDUCE16(ty_); REDUCE16(tz_); REDUCE16(tw_);    \
              float pv_ = tx_;                                               \
              pv_ = (l15 == 1) ? ty_ : pv_;                                  \
              pv_ = (l15 == 2) ? tz_ : pv_;                                  \
              pv_ = (l15 == 3) ? tw_ : pv_;                                  \
              if (l15 < 4) {                                                 \
                const int col_ = (i_ >> 1) * 32 + lg * 8 + (i_ & 1) * 4 + l15; \
                atomicAdd(&pooled[(size_t)g_ * 256 + col_], pv_);            \
              }                                                              \
            }                                                                \
            if (l == 0) atomicAdd(&segsum[g_], ss_);                         \
          }                                                                  \
          r_ = rend_;                                                        \
        }                                                                    \
        if (rend_ >= nmax_) break;                                           \
        ++g_; nb_ = offs[g_ + 1];                                            \
      }                                                                      \
    } } while (0)

  float4 xbA[16], xbB[16];
  ISSUE(xbA, tbase);
  #pragma unroll
  for (int p = 0; p < TPW / 2; ++p) {
    ISSUE(xbB, tbase + 2 * p + 1);
    PROCESS(xbA, tbase + 2 * p);
    if (2 * p + 2 < TPW) ISSUE(xbA, tbase + 2 * p + 2);
    PROCESS(xbB, tbase + 2 * p + 1);
  }
#undef ISSUE
#undef PROCESS
}

// Finalize: pooled /= segsum (0 for empty graphs), weights = exp/segsum[batch].
__global__ void finalize(float* __restrict__ pooled, float* __restrict__ wts,
                         const float* __restrict__ segsum,
                         const void* __restrict__ batch, int N)
{
  int f = blockIdx.x * 256 + threadIdx.x;
  if (f < NGRAPH * 256) {
    int g = f >> 8;
    float s = segsum[g];
    pooled[f] = (s > 0.f) ? pooled[f] / s : 0.f;
  } else {
    int n = f - NGRAPH * 256;
    if (n < N) {
      const int is64 = batch_is64(batch, N);
      int g = (int)getb(batch, n, is64);
      wts[n] = wts[n] / segsum[g];
    }
  }
}

extern "C" void kernel_launch(void* const* d_in, const int* in_sizes, int n_in,
                              void* d_out, int out_size, void* d_ws, size_t ws_size,
                              hipStream_t stream) {
  const float* x     = (const float*)d_in[0];
  const void*  batch = d_in[1];
  const float* W1    = (const float*)d_in[2];
  const float* b1    = (const float*)d_in[3];
  const float* W2    = (const float*)d_in[4];
  const float* b2    = (const float*)d_in[5];
  const int N = in_sizes[0] / 256;
  const int ntiles = (N + 15) / 16;
  const int nwaves = (ntiles + TPW - 1) / TPW;
  const int nblocks = (nwaves + 3) / 4;

  float* pooled = (float*)d_out;                          // 4096*256
  float* wout   = (float*)d_out + (size_t)NGRAPH * 256;   // N: exp(s), then weights
  s16x8* w1p    = (s16x8*)d_ws;                           // 64 KB
  int*   offs   = (int*)((char*)d_ws + 64 * 1024);        // 4097 * 4 B
  float* segsum = (float*)((char*)d_ws + 96 * 1024);      // 4096 * 4 B

  // Atomic accumulators must start at zero EVERY call (graph replays included).
  hipMemsetAsync(pooled, 0, (size_t)NGRAPH * 256 * sizeof(float), stream);
  hipMemsetAsync(segsum, 0, (size_t)NGRAPH * sizeof(float), stream);

  prepack_w1<<<16, 256, 0, stream>>>(W1, w1p);
  seg_offsets<<<17, 256, 0, stream>>>(batch, offs, N);
  gate_pool<<<nblocks, 256, 0, stream>>>(x, offs, b1, W2, b2, w1p,
                                         pooled, wout, segsum, N, ntiles);
  const int tot = NGRAPH * 256 + N;
  finalize<<<(tot + 255) / 256, 256, 0, stream>>>(pooled, wout, segsum, batch, N);
}

// Round 16
// 195.069 us; speedup vs baseline: 1.4908x; 1.2955x over previous
//
#include <hip/hip_runtime.h>
#include <hip/hip_bf16.h>

#define NGRAPH 4096

typedef __attribute__((ext_vector_type(8))) short s16x8;
typedef __attribute__((ext_vector_type(4))) float f32x4;
typedef unsigned int u32;

__device__ inline short f2bf(float f) {
  unsigned u = __float_as_uint(f);
  unsigned r = u + 0x7fffu + ((u >> 16) & 1u);
  return (short)(r >> 16);
}

// Prepack W1 (256x128 fp32, row-major) into bf16 MFMA B-fragment order.
// Fragment f = kt*8 + ct (kt,ct in 0..7). Lane l supplies B[k][c] for
// k = kt*32 + (l>>4)*8 + e (e=0..7), c = ct*16 + (l&15).
__global__ void prepack_w1(const float* __restrict__ W1, s16x8* __restrict__ w1p) {
  int t = blockIdx.x * 256 + threadIdx.x;   // 4096 threads total
  int f = t >> 6, l = t & 63;
  int kt = f >> 3, ct = f & 7;
  int k0 = kt * 32 + ((l >> 4) * 8);
  int c  = ct * 16 + (l & 15);
  s16x8 v;
  #pragma unroll
  for (int e = 0; e < 8; ++e) v[e] = f2bf(W1[(k0 + e) * 128 + c]);
  w1p[f * 64 + l] = v;
}

__device__ inline long long getb(const void* b, int i, int is64) {
  if (is64) return ((const long long*)b)[i];
  return (long long)((const int*)b)[i];
}

__device__ inline int lowb(const void* b, int n, long long v, int is64) {
  int lo = 0, hi = n;
  while (lo < hi) {
    int mid = (lo + hi) >> 1;
    if (getb(b, mid, is64) < v) lo = mid + 1; else hi = mid;
  }
  return lo;
}

__device__ inline int batch_is64(const void* batch, int N) {
  // int64 vs int32 materialization probe: an odd 32-bit word index has a zero
  // high word under int64 (values < 2^31), a near-max sorted id under int32.
  int probe = ((N & 1) == 0) ? (N - 1) : (N - 2);
  return (((const int*)batch)[probe] == 0) ? 1 : 0;
}

// One-time: offs[g] = lower_bound(batch, g).
__global__ void seg_offsets(const void* __restrict__ batch, int* __restrict__ offs, int N) {
  int g = blockIdx.x * 256 + threadIdx.x;
  const int is64 = batch_is64(batch, N);
  if (g <= NGRAPH) offs[g] = lowb(batch, N, (long long)g, is64);
}

__device__ inline float fast_tanh(float v) {
  v = fminf(fmaxf(v, -15.f), 15.f);
  float e = __expf(2.f * v);
  return __fdividef(e - 1.f, e + 1.f);
}

__device__ inline void dma16(const float* src, char* ldsdst) {
  __builtin_amdgcn_global_load_lds(
      (const __attribute__((address_space(1))) u32*)src,
      (__attribute__((address_space(3))) u32*)ldsdst,
      16, 0, 0);   // 16 B/lane: lane l -> ldsdst + l*16
}

// R11 structure + counted-vmcnt DOUBLE BUFFER (T3/T4 minimum pattern).
// Block = 2 consecutive 32-row tiles, dbuf LDS (66 KB -> 2 blocks/CU).
//   preload (b1,W2,B-frags->regs, g/offs lookups)   <- before any DMA, so no
//                                                      later wait drains t1
//   issue DMA(t0)->buf0, DMA(t1)->buf1
//   vmcnt(8): t0 ready, t1's 8 DMAs STAY IN FLIGHT; raw s_barrier
//   compute t0 (LDS+regs only)  <- t1's DMA latency hides under this
//   vmcnt(0); raw s_barrier; compute t1
// B-fragments MUST be register-resident: any VMEM load consumed inside the
// t0-compute would make the compiler drain the t1 prefetch (in-order vmcnt).
// g = batch[node0] directly (sorted batch: containing graph IS the value).
// Scores bounded (|s| <= ||W2||_1 + |b2| ~ 9) -> exp without max-subtraction.
// Cross-tile segment joins via atomicAdd (buffers zeroed every call).
__global__ __launch_bounds__(256, 2)
void gate_pool(const float* __restrict__ x, const int* __restrict__ offs,
               const void* __restrict__ batch,
               const float* __restrict__ b1, const float* __restrict__ W2,
               const float* __restrict__ b2p, const s16x8* __restrict__ w1p,
               float* __restrict__ pooled, float* __restrict__ expout,
               float* __restrict__ segsum, int N, int ntiles)
{
  __shared__ __align__(16) char buf[2][32 * 1024];  // [tile][row][swz 16B chunks]
  __shared__ float sp[2][32];   // [colhalf][node_local] partial scores
  __shared__ float sw[32];      // exp(score) per local row

  const int tid = threadIdx.x;
  const int w = tid >> 6, l = tid & 63;
  const int colhalf = w & 1, wp = w >> 1;
  const int l15 = l & 15, lg = l >> 4;

  const int node0_0 = blockIdx.x * 64;
  const int node0_1 = node0_0 + 32;
  const int has_t1 = (blockIdx.x * 2 + 1 < ntiles);

  // ---- preload phase (ALL VMEM whose results t0-compute needs) ----
  float b1v[4], w2v[4];
  #pragma unroll
  for (int ct = 0; ct < 4; ++ct) {
    int c = colhalf * 64 + ct * 16 + l15;
    b1v[ct] = b1[c];
    w2v[ct] = W2[c];
  }
  const float b2s = b2p[0];

  s16x8 bf[4][8];               // this wave's 32 B-fragments (128 VGPR)
  #pragma unroll
  for (int ctl = 0; ctl < 4; ++ctl)
    #pragma unroll
    for (int kt = 0; kt < 8; ++kt)
      bf[ctl][kt] = w1p[(kt * 8 + colhalf * 4 + ctl) * 64 + l];

  const int is64 = batch_is64(batch, N);
  const int g0 = (int)getb(batch, node0_0, is64);          // graph of node0_0
  const int nb0 = offs[g0 + 1];
  int g1 = 0, nb1 = 0;
  if (has_t1) {
    g1 = (int)getb(batch, min(node0_1, N - 1), is64);
    nb1 = offs[g1 + 1];
  }
  __builtin_amdgcn_sched_barrier(0);

  // ---- issue DMAs: 8/wave for t0 -> buf[0], 8/wave for t1 -> buf[1] ----
  #pragma unroll
  for (int i = 0; i < 8; ++i) {
    const int r = i * 4 + w;
    int grow = node0_0 + r;
    if (grow >= N) grow = N - 1;
    dma16(x + (size_t)grow * 256 + ((l ^ (r & 7)) << 2), buf[0] + r * 1024);
  }
  if (has_t1) {
    #pragma unroll
    for (int i = 0; i < 8; ++i) {
      const int r = i * 4 + w;
      int grow = node0_1 + r;
      if (grow >= N) grow = N - 1;
      dma16(x + (size_t)grow * 256 + ((l ^ (r & 7)) << 2), buf[1] + r * 1024);
    }
  }
  __builtin_amdgcn_sched_barrier(0);

  // ---- counted wait: t0 (and all preloads) done; t1's 8 stay in flight ----
  if (has_t1) { asm volatile("s_waitcnt vmcnt(8)" ::: "memory"); }
  else        { asm volatile("s_waitcnt vmcnt(0)" ::: "memory"); }
  __builtin_amdgcn_s_barrier();
  __builtin_amdgcn_sched_barrier(0);

#define PROCESS_TILE(TB, NODE0, GSTART, NBSTART) do {                         \
    /* Phase A: MFMA scores; pair wp owns rows wp*16..+15 */                  \
    {                                                                         \
      const int r0_ = wp * 16 + l15;                                          \
      const char* p0_ = (TB) + r0_ * 1024;                                    \
      const int s0_ = (r0_ & 7);                                              \
      f32x4 a0_={0.f,0.f,0.f,0.f}, a1_={0.f,0.f,0.f,0.f};                     \
      f32x4 a2_={0.f,0.f,0.f,0.f}, a3_={0.f,0.f,0.f,0.f};                     \
      _Pragma("unroll")                                                       \
      for (int kt_ = 0; kt_ < 8; ++kt_) {                                     \
        const int cc_ = kt_ * 8 + lg * 2;                                     \
        float4 xa_ = *(const float4*)(p0_ + (((cc_    ) ^ s0_) << 4));        \
        float4 xb_ = *(const float4*)(p0_ + (((cc_ + 1) ^ s0_) << 4));        \
        s16x8 a_;                                                             \
        a_[0]=f2bf(xa_.x); a_[1]=f2bf(xa_.y); a_[2]=f2bf(xa_.z); a_[3]=f2bf(xa_.w); \
        a_[4]=f2bf(xb_.x); a_[5]=f2bf(xb_.y); a_[6]=f2bf(xb_.z); a_[7]=f2bf(xb_.w); \
        a0_ = __builtin_amdgcn_mfma_f32_16x16x32_bf16(a_, bf[0][kt_], a0_,0,0,0); \
        a1_ = __builtin_amdgcn_mfma_f32_16x16x32_bf16(a_, bf[1][kt_], a1_,0,0,0); \
        a2_ = __builtin_amdgcn_mfma_f32_16x16x32_bf16(a_, bf[2][kt_], a2_,0,0,0); \
        a3_ = __builtin_amdgcn_mfma_f32_16x16x32_bf16(a_, bf[3][kt_], a3_,0,0,0); \
      }                                                                       \
      float part_[4];                                                         \
      _Pragma("unroll")                                                       \
      for (int r_ = 0; r_ < 4; ++r_) {                                        \
        part_[r_] = colhalf ? 0.f : b2s;                                      \
        part_[r_] += fast_tanh(a0_[r_] + b1v[0]) * w2v[0];                    \
        part_[r_] += fast_tanh(a1_[r_] + b1v[1]) * w2v[1];                    \
        part_[r_] += fast_tanh(a2_[r_] + b1v[2]) * w2v[2];                    \
        part_[r_] += fast_tanh(a3_[r_] + b1v[3]) * w2v[3];                    \
      }                                                                       \
      _Pragma("unroll")                                                       \
      for (int m_ = 1; m_ <= 8; m_ <<= 1) {                                   \
        _Pragma("unroll")                                                     \
        for (int r_ = 0; r_ < 4; ++r_) part_[r_] += __shfl_xor(part_[r_], m_, 64); \
      }                                                                       \
      if (l15 == 0) {                                                         \
        _Pragma("unroll")                                                     \
        for (int r_ = 0; r_ < 4; ++r_)                                        \
          sp[colhalf][wp * 16 + lg * 4 + r_] = part_[r_];                     \
      }                                                                       \
    }                                                                         \
    asm volatile("s_waitcnt lgkmcnt(0)" ::: "memory");                        \
    __builtin_amdgcn_s_barrier();                                             \
    __builtin_amdgcn_sched_barrier(0);                                        \
    if (tid < 32) {                                                           \
      int node_ = (NODE0) + tid;                                              \
      float e_ = 0.f;                                                         \
      if (node_ < N) {                                                        \
        e_ = __expf(sp[0][tid] + sp[1][tid]);                                 \
        expout[node_] = e_;                                                   \
      }                                                                       \
      sw[tid] = e_;                                                           \
    }                                                                         \
    asm volatile("s_waitcnt lgkmcnt(0)" ::: "memory");                        \
    __builtin_amdgcn_s_barrier();                                             \
    __builtin_amdgcn_sched_barrier(0);                                        \
    /* Phase B: pooling from LDS, col = tid */                                \
    {                                                                         \
      const int nmax_ = min(32, N - (NODE0));                                 \
      int g_ = (GSTART);                                                      \
      int nb_ = (NBSTART);                                                    \
      const int ccb_ = tid >> 2, cib_ = (tid & 3) << 2;                       \
      int r_ = 0;                                                             \
      while (r_ < nmax_) {                                                    \
        const int rend_ = min(nb_ - (NODE0), nmax_);                          \
        float pacc_ = 0.f, wsum_ = 0.f;                                       \
        for (; r_ + 4 <= rend_; r_ += 4) {                                    \
          float xv_[4], wv_[4];                                               \
          _Pragma("unroll")                                                   \
          for (int u_ = 0; u_ < 4; ++u_) {                                    \
            const int rr_ = r_ + u_;                                          \
            xv_[u_] = *(const float*)((TB) + rr_ * 1024 +                     \
                        (((ccb_ ^ (rr_ & 7)) << 4) | cib_));                  \
            wv_[u_] = sw[rr_];                                                \
          }                                                                   \
          _Pragma("unroll")                                                   \
          for (int u_ = 0; u_ < 4; ++u_) {                                    \
            pacc_ += wv_[u_] * xv_[u_];                                       \
            wsum_ += wv_[u_];                                                 \
          }                                                                   \
        }                                                                     \
        for (; r_ < rend_; ++r_) {                                            \
          float wv_ = sw[r_];                                                 \
          pacc_ += wv_ * *(const float*)((TB) + r_ * 1024 +                   \
                        (((ccb_ ^ (r_ & 7)) << 4) | cib_));                   \
          wsum_ += wv_;                                                       \
        }                                                                     \
        if (wsum_ > 0.f) {                                                    \
          atomicAdd(&pooled[(size_t)g_ * 256 + tid], pacc_);                  \
          if (tid == 0) atomicAdd(&segsum[g_], wsum_);                        \
        }                                                                     \
        if (rend_ >= nmax_) break;                                            \
        ++g_;                                                                 \
        nb_ = offs[g_ + 1];                                                   \
      }                                                                       \
    } } while (0)

  PROCESS_TILE(buf[0], node0_0, g0, nb0);

  asm volatile("s_waitcnt vmcnt(0)" ::: "memory");   // t1 DMAs (+atomics) done
  __builtin_amdgcn_s_barrier();
  __builtin_amdgcn_sched_barrier(0);

  if (has_t1) PROCESS_TILE(buf[1], node0_1, g1, nb1);
#undef PROCESS_TILE
}

// Finalize: pooled /= segsum (0 for empty graphs), weights = exp/segsum[batch].
__global__ void finalize(float* __restrict__ pooled, float* __restrict__ wts,
                         const float* __restrict__ segsum,
                         const void* __restrict__ batch, int N)
{
  int f = blockIdx.x * 256 + threadIdx.x;
  if (f < NGRAPH * 256) {
    int g = f >> 8;
    float s = segsum[g];
    pooled[f] = (s > 0.f) ? pooled[f] / s : 0.f;
  } else {
    int n = f - NGRAPH * 256;
    if (n < N) {
      const int is64 = batch_is64(batch, N);
      int g = (int)getb(batch, n, is64);
      wts[n] = wts[n] / segsum[g];
    }
  }
}

extern "C" void kernel_launch(void* const* d_in, const int* in_sizes, int n_in,
                              void* d_out, int out_size, void* d_ws, size_t ws_size,
                              hipStream_t stream) {
  const float* x     = (const float*)d_in[0];
  const void*  batch = d_in[1];
  const float* W1    = (const float*)d_in[2];
  const float* b1    = (const float*)d_in[3];
  const float* W2    = (const float*)d_in[4];
  const float* b2    = (const float*)d_in[5];
  const int N = in_sizes[0] / 256;
  const int ntiles = (N + 31) / 32;
  const int nblocks = (ntiles + 1) / 2;

  float* pooled = (float*)d_out;                          // 4096*256
  float* wout   = (float*)d_out + (size_t)NGRAPH * 256;   // N: exp(s), then weights
  s16x8* w1p    = (s16x8*)d_ws;                           // 64 KB
  int*   offs   = (int*)((char*)d_ws + 64 * 1024);        // 4097 * 4 B
  float* segsum = (float*)((char*)d_ws + 96 * 1024);      // 4096 * 4 B

  // Atomic accumulators must start at zero EVERY call (graph replays included).
  hipMemsetAsync(pooled, 0, (size_t)NGRAPH * 256 * sizeof(float), stream);
  hipMemsetAsync(segsum, 0, (size_t)NGRAPH * sizeof(float), stream);

  prepack_w1<<<16, 256, 0, stream>>>(W1, w1p);
  seg_offsets<<<17, 256, 0, stream>>>(batch, offs, N);
  gate_pool<<<nblocks, 256, 0, stream>>>(x, offs, batch, b1, W2, b2, w1p,
                                         pooled, wout, segsum, N, ntiles);
  const int tot = NGRAPH * 256 + N;
  finalize<<<(tot + 255) / 256, 256, 0, stream>>>(pooled, wout, segsum, batch, N);
}

// Round 17
// 188.528 us; speedup vs baseline: 1.5425x; 1.0347x over previous
//
#include <hip/hip_runtime.h>
#include <hip/hip_bf16.h>

#define NGRAPH 4096

typedef __attribute__((ext_vector_type(8))) short s16x8;
typedef __attribute__((ext_vector_type(4))) float f32x4;
typedef unsigned int u32;

__device__ inline short f2bf(float f) {
  unsigned u = __float_as_uint(f);
  unsigned r = u + 0x7fffu + ((u >> 16) & 1u);
  return (short)(r >> 16);
}

// Prepack W1 (256x128 fp32, row-major) into bf16 MFMA B-fragment order.
// Fragment f = kt*8 + ct (kt,ct in 0..7). Lane l supplies B[k][c] for
// k = kt*32 + (l>>4)*8 + e (e=0..7), c = ct*16 + (l&15).
__global__ void prepack_w1(const float* __restrict__ W1, s16x8* __restrict__ w1p) {
  int t = blockIdx.x * 256 + threadIdx.x;   // 4096 threads total
  int f = t >> 6, l = t & 63;
  int kt = f >> 3, ct = f & 7;
  int k0 = kt * 32 + ((l >> 4) * 8);
  int c  = ct * 16 + (l & 15);
  s16x8 v;
  #pragma unroll
  for (int e = 0; e < 8; ++e) v[e] = f2bf(W1[(k0 + e) * 128 + c]);
  w1p[f * 64 + l] = v;
}

__device__ inline long long getb(const void* b, int i, int is64) {
  if (is64) return ((const long long*)b)[i];
  return (long long)((const int*)b)[i];
}

__device__ inline int lowb(const void* b, int n, long long v, int is64) {
  int lo = 0, hi = n;
  while (lo < hi) {
    int mid = (lo + hi) >> 1;
    if (getb(b, mid, is64) < v) lo = mid + 1; else hi = mid;
  }
  return lo;
}

__device__ inline int batch_is64(const void* batch, int N) {
  // int64 vs int32 materialization probe: an odd 32-bit word index has a zero
  // high word under int64 (values < 2^31), a near-max sorted id under int32.
  int probe = ((N & 1) == 0) ? (N - 1) : (N - 2);
  return (((const int*)batch)[probe] == 0) ? 1 : 0;
}

// One-time: offs[g] = lower_bound(batch, g).
__global__ void seg_offsets(const void* __restrict__ batch, int* __restrict__ offs, int N) {
  int g = blockIdx.x * 256 + threadIdx.x;
  const int is64 = batch_is64(batch, N);
  if (g <= NGRAPH) offs[g] = lowb(batch, N, (long long)g, is64);
}

__device__ inline float fast_tanh(float v) {
  v = fminf(fmaxf(v, -15.f), 15.f);
  float e = __expf(2.f * v);
  return __fdividef(e - 1.f, e + 1.f);
}

// R11 structure with REG-STAGED x loads (instead of global_load_lds).
// Motivation: R14/R15 (plain loads) showed FETCH_SIZE ~= 251 MB -- half of x
// served by the 256 MB Infinity Cache across graph replays -- while the DMA
// path fetched the full ~518 MB every call (R8/R10 counters). Plain loads
// allocate in L3; the DMA reads appear not to. Reg-staging: contiguous
// coalesced read (lane l reads bytes [16l,16l+16) of the row), then
// ds_write_b128 to LDS chunk (l ^ (row&7)) -- stored layout is identical to
// the dma16 version, so phase A/B read code is untouched (Guideline 21).
// 32-row tiles, 3 blocks/CU. Phase A: MFMA gate scores from LDS (wave-pair
// owns 16 rows, colhalf owns 64 of 128 hidden cols, B-frags inline from
// L2-resident w1p). Phase B: pooling from LDS.
// Scores bounded (|s| <= ||W2||_1 + |b2| ~ 9) -> exp without max-subtraction.
// Cross-block segment joins via atomicAdd (buffers zeroed every call).
__global__ __launch_bounds__(256, 3)
void gate_pool(const float* __restrict__ x, const int* __restrict__ offs,
               const float* __restrict__ b1, const float* __restrict__ W2,
               const float* __restrict__ b2p, const s16x8* __restrict__ w1p,
               float* __restrict__ pooled, float* __restrict__ expout,
               float* __restrict__ segsum, int N)
{
  __shared__ __align__(16) char tile[32 * 1024];  // [row][swizzled 16B chunks]
  __shared__ float sp[2][32];   // [colhalf][node_local] partial scores
  __shared__ float sw[32];      // exp(score) per local row

  const int tid = threadIdx.x;
  const int w = tid >> 6, l = tid & 63;
  const int colhalf = w & 1, wp = w >> 1;
  const int l15 = l & 15, lg = l >> 4;
  const int node0 = blockIdx.x * 32;

  // ---- reg-staged x loads: wave w owns rows w, w+4, ..., w+28 ----
  // (1) issue all 8 contiguous row loads (L3-allocating plain loads)
  float4 stg[8];
  #pragma unroll
  for (int i = 0; i < 8; ++i) {
    const int r = i * 4 + w;                 // local row (wave-uniform)
    int grow = node0 + r;
    if (grow >= N) grow = N - 1;             // pad rows: discarded later
    stg[i] = *(const float4*)(x + (size_t)grow * 256 + (l << 2));
  }

  float b1v[4], w2v[4];
  #pragma unroll
  for (int ct = 0; ct < 4; ++ct) {
    int c = colhalf * 64 + ct * 16 + l15;
    b1v[ct] = b1[c];
    w2v[ct] = W2[c];
  }
  const float b2s = b2p[0];

  // (2) swizzled ds_write: lane l's source chunk l -> LDS chunk l^(r&7),
  //     identical stored layout to the previous dma16 version
  #pragma unroll
  for (int i = 0; i < 8; ++i) {
    const int r = i * 4 + w;
    *(float4*)(tile + r * 1024 + ((l ^ (r & 7)) << 4)) = stg[i];
  }

  __syncthreads();   // waits ds_writes (lgkmcnt) -> tile ready

  // ---- Phase A: MFMA gate scores; wave-pair wp owns local rows wp*16..+15,
  //      A-fragments from LDS, B inline from L2-resident w1p ----
  {
    const int r0 = wp * 16 + l15;
    const char* p0 = tile + r0 * 1024;
    const int s0 = (r0 & 7);

    f32x4 acc0 = {0.f,0.f,0.f,0.f}, acc1 = {0.f,0.f,0.f,0.f};
    f32x4 acc2 = {0.f,0.f,0.f,0.f}, acc3 = {0.f,0.f,0.f,0.f};
    #pragma unroll
    for (int kt = 0; kt < 8; ++kt) {
      const int cc = kt * 8 + lg * 2;        // 16B-chunk index of 8-float slab
      float4 xa = *(const float4*)(p0 + (((cc    ) ^ s0) << 4));
      float4 xb = *(const float4*)(p0 + (((cc + 1) ^ s0) << 4));
      const s16x8* wb = w1p + (kt * 8 + colhalf * 4) * 64 + l;   // L2-resident
      s16x8 bf0 = wb[0], bf1 = wb[64], bf2 = wb[128], bf3 = wb[192];
      s16x8 a;
      a[0] = f2bf(xa.x); a[1] = f2bf(xa.y); a[2] = f2bf(xa.z); a[3] = f2bf(xa.w);
      a[4] = f2bf(xb.x); a[5] = f2bf(xb.y); a[6] = f2bf(xb.z); a[7] = f2bf(xb.w);
      acc0 = __builtin_amdgcn_mfma_f32_16x16x32_bf16(a, bf0, acc0, 0, 0, 0);
      acc1 = __builtin_amdgcn_mfma_f32_16x16x32_bf16(a, bf1, acc1, 0, 0, 0);
      acc2 = __builtin_amdgcn_mfma_f32_16x16x32_bf16(a, bf2, acc2, 0, 0, 0);
      acc3 = __builtin_amdgcn_mfma_f32_16x16x32_bf16(a, bf3, acc3, 0, 0, 0);
    }
    // h = tanh(acc + b1); partial score = sum h*W2 over this wave's 64 cols.
    // D layout: node-in-tile = 4*lg + r, hidden-col = ct*16 + l15.
    float part[4];
    #pragma unroll
    for (int r = 0; r < 4; ++r) {
      part[r] = colhalf ? 0.f : b2s;
      part[r] += fast_tanh(acc0[r] + b1v[0]) * w2v[0];
      part[r] += fast_tanh(acc1[r] + b1v[1]) * w2v[1];
      part[r] += fast_tanh(acc2[r] + b1v[2]) * w2v[2];
      part[r] += fast_tanh(acc3[r] + b1v[3]) * w2v[3];
    }
    #pragma unroll
    for (int m = 1; m <= 8; m <<= 1) {
      #pragma unroll
      for (int r = 0; r < 4; ++r) part[r] += __shfl_xor(part[r], m, 64);
    }
    if (l15 == 0) {
      #pragma unroll
      for (int r = 0; r < 4; ++r)
        sp[colhalf][wp * 16 + lg * 4 + r] = part[r];
    }
  }
  __syncthreads();

  // combine halves, exponentiate (no max needed: |score| <= ~9), store
  if (tid < 32) {
    int node = node0 + tid;
    float e = 0.f;
    if (node < N) {
      e = __expf(sp[0][tid] + sp[1][tid]);
      expout[node] = e;                 // unnormalized weight, fixed in finalize
    }
    sw[tid] = e;
  }
  __syncthreads();

  // ---- Phase B: pooling from LDS, col = tid ----
  const int nmax = min(32, N - node0);
  // g: graph containing node0 (upper_bound on offs)
  int g;
  {
    int lo = 0, hi = NGRAPH - 1;
    while (lo < hi) {
      int mid = (lo + hi) >> 1;
      if (offs[mid + 1] <= node0) lo = mid + 1; else hi = mid;
    }
    g = lo;
  }
  const int ccb = tid >> 2, cib = (tid & 3) << 2;   // chunk + in-chunk byte
  int r = 0;
  int nb = offs[g + 1];
  while (r < nmax) {
    const int rend = min(nb - node0, nmax);
    float pacc = 0.f, wsum = 0.f;
    for (; r + 8 <= rend; r += 8) {
      float xv[8], wv[8];
      #pragma unroll
      for (int u = 0; u < 8; ++u) {
        const int rr = r + u;
        xv[u] = *(const float*)(tile + rr * 1024 + (((ccb ^ (rr & 7)) << 4) | cib));
        wv[u] = sw[rr];
      }
      #pragma unroll
      for (int u = 0; u < 8; ++u) {
        pacc += wv[u] * xv[u];
        wsum += wv[u];
      }
    }
    for (; r < rend; ++r) {
      float wv = sw[r];
      pacc += wv * *(const float*)(tile + r * 1024 + (((ccb ^ (r & 7)) << 4) | cib));
      wsum += wv;
    }
    if (wsum > 0.f) {
      atomicAdd(&pooled[(size_t)g * 256 + tid], pacc);
      if (tid == 0) atomicAdd(&segsum[g], wsum);
    }
    if (rend >= nmax) break;
    ++g;
    nb = offs[g + 1];
  }
}

// Finalize: pooled /= segsum (0 for empty graphs), weights = exp/segsum[batch].
__global__ void finalize(float* __restrict__ pooled, float* __restrict__ wts,
                         const float* __restrict__ segsum,
                         const void* __restrict__ batch, int N)
{
  int f = blockIdx.x * 256 + threadIdx.x;
  if (f < NGRAPH * 256) {
    int g = f >> 8;
    float s = segsum[g];
    pooled[f] = (s > 0.f) ? pooled[f] / s : 0.f;
  } else {
    int n = f - NGRAPH * 256;
    if (n < N) {
      const int is64 = batch_is64(batch, N);
      int g = (int)getb(batch, n, is64);
      wts[n] = wts[n] / segsum[g];
    }
  }
}

extern "C" void kernel_launch(void* const* d_in, const int* in_sizes, int n_in,
                              void* d_out, int out_size, void* d_ws, size_t ws_size,
                              hipStream_t stream) {
  const float* x     = (const float*)d_in[0];
  const void*  batch = d_in[1];
  const float* W1    = (const float*)d_in[2];
  const float* b1    = (const float*)d_in[3];
  const float* W2    = (const float*)d_in[4];
  const float* b2    = (const float*)d_in[5];
  const int N = in_sizes[0] / 256;

  float* pooled = (float*)d_out;                          // 4096*256
  float* wout   = (float*)d_out + (size_t)NGRAPH * 256;   // N: exp(s), then weights
  s16x8* w1p    = (s16x8*)d_ws;                           // 64 KB
  int*   offs   = (int*)((char*)d_ws + 64 * 1024);        // 4097 * 4 B
  float* segsum = (float*)((char*)d_ws + 96 * 1024);      // 4096 * 4 B

  // Atomic accumulators must start at zero EVERY call (graph replays included).
  hipMemsetAsync(pooled, 0, (size_t)NGRAPH * 256 * sizeof(float), stream);
  hipMemsetAsync(segsum, 0, (size_t)NGRAPH * sizeof(float), stream);

  prepack_w1<<<16, 256, 0, stream>>>(W1, w1p);
  seg_offsets<<<17, 256, 0, stream>>>(batch, offs, N);
  gate_pool<<<(N + 31) / 32, 256, 0, stream>>>(x, offs, b1, W2, b2, w1p,
                                               pooled, wout, segsum, N);
  const int tot = NGRAPH * 256 + N;
  finalize<<<(tot + 255) / 256, 256, 0, stream>>>(pooled, wout, segsum, batch, N);
}

// Round 18
// 184.914 us; speedup vs baseline: 1.5726x; 1.0195x over previous
//
#include <hip/hip_runtime.h>
#include <hip/hip_bf16.h>

#define NGRAPH 4096
#define PBLOCKS 512   // 2 persistent blocks per CU

typedef __attribute__((ext_vector_type(8))) short s16x8;
typedef __attribute__((ext_vector_type(4))) float f32x4;
typedef unsigned int u32;

__device__ inline short f2bf(float f) {
  unsigned u = __float_as_uint(f);
  unsigned r = u + 0x7fffu + ((u >> 16) & 1u);
  return (short)(r >> 16);
}

// Prepack W1 (256x128 fp32, row-major) into bf16 MFMA B-fragment order.
// Fragment f = kt*8 + ct (kt,ct in 0..7). Lane l supplies B[k][c] for
// k = kt*32 + (l>>4)*8 + e (e=0..7), c = ct*16 + (l&15).
__global__ void prepack_w1(const float* __restrict__ W1, s16x8* __restrict__ w1p) {
  int t = blockIdx.x * 256 + threadIdx.x;   // 4096 threads total
  int f = t >> 6, l = t & 63;
  int kt = f >> 3, ct = f & 7;
  int k0 = kt * 32 + ((l >> 4) * 8);
  int c  = ct * 16 + (l & 15);
  s16x8 v;
  #pragma unroll
  for (int e = 0; e < 8; ++e) v[e] = f2bf(W1[(k0 + e) * 128 + c]);
  w1p[f * 64 + l] = v;
}

__device__ inline long long getb(const void* b, int i, int is64) {
  if (is64) return ((const long long*)b)[i];
  return (long long)((const int*)b)[i];
}

__device__ inline int lowb(const void* b, int n, long long v, int is64) {
  int lo = 0, hi = n;
  while (lo < hi) {
    int mid = (lo + hi) >> 1;
    if (getb(b, mid, is64) < v) lo = mid + 1; else hi = mid;
  }
  return lo;
}

__device__ inline int batch_is64(const void* batch, int N) {
  // int64 vs int32 materialization probe: an odd 32-bit word index has a zero
  // high word under int64 (values < 2^31), a near-max sorted id under int32.
  int probe = ((N & 1) == 0) ? (N - 1) : (N - 2);
  return (((const int*)batch)[probe] == 0) ? 1 : 0;
}

// One-time: offs[g] = lower_bound(batch, g).
__global__ void seg_offsets(const void* __restrict__ batch, int* __restrict__ offs, int N) {
  int g = blockIdx.x * 256 + threadIdx.x;
  const int is64 = batch_is64(batch, N);
  if (g <= NGRAPH) offs[g] = lowb(batch, N, (long long)g, is64);
}

// One-time: per-tile segment metadata so the hot loop does NO dependent
// offs/batch loads. meta[t] = {g(first graph in tile), offs[g+1], offs[g+2],
// offs[g+3]} -- covers 3 segment crossings; >3 falls back to a lazy load
// (astronomically rare: mean graph size ~122 rows vs 32-row tiles).
__global__ void tile_meta(const void* __restrict__ batch, const int* __restrict__ offs,
                          int4* __restrict__ meta, int N, int ntiles) {
  int t = blockIdx.x * 256 + threadIdx.x;
  if (t >= ntiles) return;
  const int is64 = batch_is64(batch, N);
  int node = t * 32; if (node >= N) node = N - 1;
  int g = (int)getb(batch, node, is64);
  meta[t] = make_int4(g, offs[g + 1],
                      offs[min(g + 2, NGRAPH)], offs[min(g + 3, NGRAPH)]);
}

__device__ inline float fast_tanh(float v) {
  v = fminf(fmaxf(v, -15.f), 15.f);
  float e = __expf(2.f * v);
  return __fdividef(e - 1.f, e + 1.f);
}

__device__ inline void dma16(const float* src, char* ldsdst) {
  __builtin_amdgcn_global_load_lds(
      (const __attribute__((address_space(1))) u32*)src,
      (__attribute__((address_space(3))) u32*)ldsdst,
      16, 0, 0);   // 16 B/lane: lane l -> ldsdst + l*16
}

// PERSISTENT DBUF: 512 blocks (2/CU) grid-stride over 32-row tiles.
// Steady-state iteration:
//   [ld int4 meta(next)] [issue 8 DMAs(next) -> buf^1]   <- prefetch spans...
//   [compute cur: phase A (MFMA, LDS+reg only), exp, phase B]  <- ...this
//   [vmcnt(0); s_barrier]                                 <- residual drain
// The ONLY consumed VMEM between prefetch-issue and tile-end is the rare
// lazy offs load -- so no compiler wait drains the prefetch (in-order vmcnt).
// B-fragments in registers (128 VGPR); biases/W2 in regs; meta in regs.
// Barriers are raw s_barrier + lgkmcnt (never __syncthreads: its vmcnt(0)
// would kill the prefetch). Scores bounded (|s|<=~9) -> exp without max.
// Cross-tile segment joins via atomicAdd (buffers zeroed every call).
__global__ __launch_bounds__(256, 2)
void gate_pool(const float* __restrict__ x, const int4* __restrict__ meta,
               const int* __restrict__ offs,
               const float* __restrict__ b1, const float* __restrict__ W2,
               const float* __restrict__ b2p, const s16x8* __restrict__ w1p,
               float* __restrict__ pooled, float* __restrict__ expout,
               float* __restrict__ segsum, int N, int ntiles)
{
  __shared__ __align__(16) char buf[2][32 * 1024];
  __shared__ float sp[2][32];   // [colhalf][row] partial scores
  __shared__ float sw[32];      // exp(score) per row

  const int tid = threadIdx.x;
  const int w = tid >> 6, l = tid & 63;
  const int colhalf = w & 1, wp = w >> 1;
  const int l15 = l & 15, lg = l >> 4;

  if (blockIdx.x >= ntiles) return;

  // ---- one-time preloads (all VMEM, before the pipeline starts) ----
  s16x8 bf[4][8];               // this wave's 32 B-fragments (128 VGPR)
  #pragma unroll
  for (int ctl = 0; ctl < 4; ++ctl)
    #pragma unroll
    for (int kt = 0; kt < 8; ++kt)
      bf[ctl][kt] = w1p[(kt * 8 + colhalf * 4 + ctl) * 64 + l];

  float b1v[4], w2v[4];
  #pragma unroll
  for (int ct = 0; ct < 4; ++ct) {
    int c = colhalf * 64 + ct * 16 + l15;
    b1v[ct] = b1[c];
    w2v[ct] = W2[c];
  }
  const float b2s = b2p[0];

  int ti = blockIdx.x;
  int4 M = meta[ti];

  // prologue: stage first tile into buf[0]
  {
    const int node0 = ti * 32;
    #pragma unroll
    for (int i = 0; i < 8; ++i) {
      const int r = i * 4 + w;
      int grow = node0 + r;
      if (grow >= N) grow = N - 1;
      dma16(x + (size_t)grow * 256 + ((l ^ (r & 7)) << 2), buf[0] + r * 1024);
    }
  }
  asm volatile("s_waitcnt vmcnt(0)" ::: "memory");
  __builtin_amdgcn_s_barrier();
  __builtin_amdgcn_sched_barrier(0);

  int par = 0;
  for (; ti < ntiles; ti += PBLOCKS) {
    const int tnext = ti + PBLOCKS;
    int4 Mnext = M;
    if (tnext < ntiles) {
      Mnext = meta[tnext];                       // older than the DMAs below:
      const int nn0 = tnext * 32;                // its wait won't drain them
      char* dst = buf[par ^ 1];
      #pragma unroll
      for (int i = 0; i < 8; ++i) {
        const int r = i * 4 + w;
        int grow = nn0 + r;
        if (grow >= N) grow = N - 1;
        dma16(x + (size_t)grow * 256 + ((l ^ (r & 7)) << 2), dst + r * 1024);
      }
    }
    __builtin_amdgcn_sched_barrier(0);

    const char* tile = buf[par];
    const int node0 = ti * 32;

    // ---- Phase A: MFMA scores; pair wp owns rows wp*16..+15 (LDS+regs) ----
    {
      const int r0 = wp * 16 + l15;
      const char* p0 = tile + r0 * 1024;
      const int s0 = (r0 & 7);
      f32x4 acc0 = {0.f,0.f,0.f,0.f}, acc1 = {0.f,0.f,0.f,0.f};
      f32x4 acc2 = {0.f,0.f,0.f,0.f}, acc3 = {0.f,0.f,0.f,0.f};
      #pragma unroll
      for (int kt = 0; kt < 8; ++kt) {
        const int cc = kt * 8 + lg * 2;
        float4 xa = *(const float4*)(p0 + (((cc    ) ^ s0) << 4));
        float4 xb = *(const float4*)(p0 + (((cc + 1) ^ s0) << 4));
        s16x8 a;
        a[0] = f2bf(xa.x); a[1] = f2bf(xa.y); a[2] = f2bf(xa.z); a[3] = f2bf(xa.w);
        a[4] = f2bf(xb.x); a[5] = f2bf(xb.y); a[6] = f2bf(xb.z); a[7] = f2bf(xb.w);
        acc0 = __builtin_amdgcn_mfma_f32_16x16x32_bf16(a, bf[0][kt], acc0, 0, 0, 0);
        acc1 = __builtin_amdgcn_mfma_f32_16x16x32_bf16(a, bf[1][kt], acc1, 0, 0, 0);
        acc2 = __builtin_amdgcn_mfma_f32_16x16x32_bf16(a, bf[2][kt], acc2, 0, 0, 0);
        acc3 = __builtin_amdgcn_mfma_f32_16x16x32_bf16(a, bf[3][kt], acc3, 0, 0, 0);
      }
      // h = tanh(acc+b1); partial score over this wave's 64 cols.
      // D layout: node-in-tile = 4*lg + r, hidden-col = ct*16 + l15.
      float part[4];
      #pragma unroll
      for (int r = 0; r < 4; ++r) {
        part[r] = colhalf ? 0.f : b2s;
        part[r] += fast_tanh(acc0[r] + b1v[0]) * w2v[0];
        part[r] += fast_tanh(acc1[r] + b1v[1]) * w2v[1];
        part[r] += fast_tanh(acc2[r] + b1v[2]) * w2v[2];
        part[r] += fast_tanh(acc3[r] + b1v[3]) * w2v[3];
      }
      #pragma unroll
      for (int m = 1; m <= 8; m <<= 1) {
        #pragma unroll
        for (int r = 0; r < 4; ++r) part[r] += __shfl_xor(part[r], m, 64);
      }
      if (l15 == 0) {
        #pragma unroll
        for (int r = 0; r < 4; ++r)
          sp[colhalf][wp * 16 + lg * 4 + r] = part[r];
      }
    }
    asm volatile("s_waitcnt lgkmcnt(0)" ::: "memory");
    __builtin_amdgcn_s_barrier();
    __builtin_amdgcn_sched_barrier(0);

    // combine halves, exponentiate (no max: |score| <= ~9), store
    if (tid < 32) {
      int node = node0 + tid;
      float e = 0.f;
      if (node < N) {
        e = __expf(sp[0][tid] + sp[1][tid]);
        expout[node] = e;
      }
      sw[tid] = e;
    }
    asm volatile("s_waitcnt lgkmcnt(0)" ::: "memory");
    __builtin_amdgcn_s_barrier();
    __builtin_amdgcn_sched_barrier(0);

    // ---- Phase B: pooling from LDS, col = tid; meta-resident offs ----
    {
      const int nmax = min(32, N - node0);
      int g = M.x;
      int nb = M.y;
      int crossing = 0;
      const int ccb = tid >> 2, cib = (tid & 3) << 2;
      int r = 0;
      while (r < nmax) {
        const int rend = min(nb - node0, nmax);
        float pacc = 0.f, wsum = 0.f;
        for (; r + 8 <= rend; r += 8) {
          float xv[8], wv[8];
          #pragma unroll
          for (int u = 0; u < 8; ++u) {
            const int rr = r + u;
            xv[u] = *(const float*)(tile + rr * 1024 + (((ccb ^ (rr & 7)) << 4) | cib));
            wv[u] = sw[rr];
          }
          #pragma unroll
          for (int u = 0; u < 8; ++u) {
            pacc += wv[u] * xv[u];
            wsum += wv[u];
          }
        }
        for (; r < rend; ++r) {
          float wv = sw[r];
          pacc += wv * *(const float*)(tile + r * 1024 + (((ccb ^ (r & 7)) << 4) | cib));
          wsum += wv;
        }
        if (wsum > 0.f) {
          atomicAdd(&pooled[(size_t)g * 256 + tid], pacc);
          if (tid == 0) atomicAdd(&segsum[g], wsum);
        }
        if (rend >= nmax) break;
        ++g; ++crossing;
        nb = (crossing == 1) ? M.z
           : (crossing == 2) ? M.w
           : offs[min(g + 1, NGRAPH)];   // lazy fallback (rare)
      }
    }

    asm volatile("s_waitcnt vmcnt(0)" ::: "memory");  // residual prefetch drain
    __builtin_amdgcn_s_barrier();
    __builtin_amdgcn_sched_barrier(0);
    M = Mnext;
    par ^= 1;
  }
}

// Finalize: pooled /= segsum (0 for empty graphs), weights = exp/segsum[batch].
__global__ void finalize(float* __restrict__ pooled, float* __restrict__ wts,
                         const float* __restrict__ segsum,
                         const void* __restrict__ batch, int N)
{
  int f = blockIdx.x * 256 + threadIdx.x;
  if (f < NGRAPH * 256) {
    int g = f >> 8;
    float s = segsum[g];
    pooled[f] = (s > 0.f) ? pooled[f] / s : 0.f;
  } else {
    int n = f - NGRAPH * 256;
    if (n < N) {
      const int is64 = batch_is64(batch, N);
      int g = (int)getb(batch, n, is64);
      wts[n] = wts[n] / segsum[g];
    }
  }
}

extern "C" void kernel_launch(void* const* d_in, const int* in_sizes, int n_in,
                              void* d_out, int out_size, void* d_ws, size_t ws_size,
                              hipStream_t stream) {
  const float* x     = (const float*)d_in[0];
  const void*  batch = d_in[1];
  const float* W1    = (const float*)d_in[2];
  const float* b1    = (const float*)d_in[3];
  const float* W2    = (const float*)d_in[4];
  const float* b2    = (const float*)d_in[5];
  const int N = in_sizes[0] / 256;
  const int ntiles = (N + 31) / 32;

  float* pooled = (float*)d_out;                          // 4096*256
  float* wout   = (float*)d_out + (size_t)NGRAPH * 256;   // N: exp(s), then weights
  s16x8* w1p    = (s16x8*)d_ws;                           // 64 KB
  int*   offs   = (int*)((char*)d_ws + 64 * 1024);        // 4097 * 4 B
  float* segsum = (float*)((char*)d_ws + 96 * 1024);      // 4096 * 4 B
  int4*  meta   = (int4*)((char*)d_ws + 128 * 1024);      // ntiles * 16 B (~250 KB)

  // Atomic accumulators must start at zero EVERY call (graph replays included).
  hipMemsetAsync(pooled, 0, (size_t)NGRAPH * 256 * sizeof(float), stream);
  hipMemsetAsync(segsum, 0, (size_t)NGRAPH * sizeof(float), stream);

  prepack_w1<<<16, 256, 0, stream>>>(W1, w1p);
  seg_offsets<<<17, 256, 0, stream>>>(batch, offs, N);
  tile_meta<<<(ntiles + 255) / 256, 256, 0, stream>>>(batch, offs, meta, N, ntiles);
  gate_pool<<<PBLOCKS, 256, 0, stream>>>(x, meta, offs, b1, W2, b2, w1p,
                                         pooled, wout, segsum, N, ntiles);
  const int tot = NGRAPH * 256 + N;
  finalize<<<(tot + 255) / 256, 256, 0, stream>>>(pooled, wout, segsum, batch, N);
}

// Round 19
// 177.423 us; speedup vs baseline: 1.6390x; 1.0422x over previous
//
#include <hip/hip_runtime.h>
#include <hip/hip_bf16.h>

#define NGRAPH 4096
#define PBLOCKS 512   // 2 persistent blocks per CU

typedef __attribute__((ext_vector_type(8))) short s16x8;
typedef __attribute__((ext_vector_type(4))) float f32x4;
typedef unsigned int u32;

__device__ inline short f2bf(float f) {
  unsigned u = __float_as_uint(f);
  unsigned r = u + 0x7fffu + ((u >> 16) & 1u);
  return (short)(r >> 16);
}

__device__ inline long long getb(const void* b, int i, int is64) {
  if (is64) return ((const long long*)b)[i];
  return (long long)((const int*)b)[i];
}

__device__ inline int lowb(const void* b, int n, long long v, int is64) {
  int lo = 0, hi = n;
  while (lo < hi) {
    int mid = (lo + hi) >> 1;
    if (getb(b, mid, is64) < v) lo = mid + 1; else hi = mid;
  }
  return lo;
}

__device__ inline int batch_is64(const void* batch, int N) {
  // int64 vs int32 materialization probe: an odd 32-bit word index has a zero
  // high word under int64 (values < 2^31), a near-max sorted id under int32.
  int probe = ((N & 1) == 0) ? (N - 1) : (N - 2);
  return (((const int*)batch)[probe] == 0) ? 1 : 0;
}

// ONE consolidated setup kernel (replaces prepack + seg_offsets + tile_meta +
// 2 hipMemsetAsync -> cuts 4 graph nodes of launch/serialization overhead).
// Block partition:
//   [0,16):          prepack W1 -> bf16 MFMA B-fragment order
//   [16,33):         offs[g] = lower_bound(batch, g)
//   [33,33+metaB):   meta[t] = {g, lb(g+1), lb(g+2), lb(g+3)} (own searches,
//                    no dependency on offs[])
//   [33+metaB, ...): zero pooled (float4 grid-stride) + segsum
__global__ void setup(const float* __restrict__ W1, const void* __restrict__ batch,
                      s16x8* __restrict__ w1p, int* __restrict__ offs,
                      int4* __restrict__ meta, float* __restrict__ pooled,
                      float* __restrict__ segsum, int N, int ntiles,
                      int metaB, int zeroB)
{
  const int b = blockIdx.x, tid = threadIdx.x;
  if (b < 16) {
    // prepack W1 (256x128 fp32, row-major) into B-fragment order.
    // Fragment f = kt*8+ct. Lane l supplies B[k][c], k = kt*32+(l>>4)*8+e,
    // c = ct*16+(l&15).
    int t = b * 256 + tid;
    int f = t >> 6, l = t & 63;
    int kt = f >> 3, ct = f & 7;
    int k0 = kt * 32 + ((l >> 4) * 8);
    int c  = ct * 16 + (l & 15);
    s16x8 v;
    #pragma unroll
    for (int e = 0; e < 8; ++e) v[e] = f2bf(W1[(k0 + e) * 128 + c]);
    w1p[f * 64 + l] = v;
  } else if (b < 33) {
    const int is64 = batch_is64(batch, N);
    int g = (b - 16) * 256 + tid;
    if (g <= NGRAPH) offs[g] = lowb(batch, N, (long long)g, is64);
  } else if (b < 33 + metaB) {
    const int is64 = batch_is64(batch, N);
    int t = (b - 33) * 256 + tid;
    if (t < ntiles) {
      int node = t * 32; if (node >= N) node = N - 1;
      int g = (int)getb(batch, node, is64);
      meta[t] = make_int4(g,
                          lowb(batch, N, (long long)(g + 1), is64),
                          lowb(batch, N, (long long)(g + 2), is64),
                          lowb(batch, N, (long long)(g + 3), is64));
    }
  } else {
    const int zb = b - 33 - metaB;
    float4* p = (float4*)pooled;
    const int tot4 = NGRAPH * 256 / 4;
    for (int i = zb * 256 + tid; i < tot4; i += zeroB * 256)
      p[i] = make_float4(0.f, 0.f, 0.f, 0.f);
    for (int i = zb * 256 + tid; i < NGRAPH; i += zeroB * 256)
      segsum[i] = 0.f;
  }
}

__device__ inline float fast_tanh(float v) {
  v = fminf(fmaxf(v, -15.f), 15.f);
  float e = __expf(2.f * v);
  return __fdividef(e - 1.f, e + 1.f);
}

__device__ inline void dma16(const float* src, char* ldsdst) {
  __builtin_amdgcn_global_load_lds(
      (const __attribute__((address_space(1))) u32*)src,
      (__attribute__((address_space(3))) u32*)ldsdst,
      16, 0, 0);   // 16 B/lane: lane l -> ldsdst + l*16
}

// PERSISTENT DBUF (identical to R18): 512 blocks (2/CU) grid-stride over
// 32-row tiles. Steady-state iteration:
//   [ld int4 meta(next)] [issue 8 DMAs(next) -> buf^1]
//   [compute cur: phase A (MFMA, LDS+reg only), exp, phase B]
//   [vmcnt(0); s_barrier]
// No consumed VMEM sits between prefetch-issue and tile-end (B-frags in
// registers, per-tile segment metadata preloaded), so no compiler wait
// drains the prefetch. Raw s_barrier + lgkmcnt only (never __syncthreads).
// Scores bounded (|s| <= ||W2||_1 + |b2| ~ 9) -> exp without max.
// Cross-tile segment joins via atomicAdd (buffers zeroed by setup).
__global__ __launch_bounds__(256, 2)
void gate_pool(const float* __restrict__ x, const int4* __restrict__ meta,
               const int* __restrict__ offs,
               const float* __restrict__ b1, const float* __restrict__ W2,
               const float* __restrict__ b2p, const s16x8* __restrict__ w1p,
               float* __restrict__ pooled, float* __restrict__ expout,
               float* __restrict__ segsum, int N, int ntiles)
{
  __shared__ __align__(16) char buf[2][32 * 1024];
  __shared__ float sp[2][32];   // [colhalf][row] partial scores
  __shared__ float sw[32];      // exp(score) per row

  const int tid = threadIdx.x;
  const int w = tid >> 6, l = tid & 63;
  const int colhalf = w & 1, wp = w >> 1;
  const int l15 = l & 15, lg = l >> 4;

  if (blockIdx.x >= ntiles) return;

  // ---- one-time preloads (all VMEM, before the pipeline starts) ----
  s16x8 bf[4][8];               // this wave's 32 B-fragments (128 VGPR)
  #pragma unroll
  for (int ctl = 0; ctl < 4; ++ctl)
    #pragma unroll
    for (int kt = 0; kt < 8; ++kt)
      bf[ctl][kt] = w1p[(kt * 8 + colhalf * 4 + ctl) * 64 + l];

  float b1v[4], w2v[4];
  #pragma unroll
  for (int ct = 0; ct < 4; ++ct) {
    int c = colhalf * 64 + ct * 16 + l15;
    b1v[ct] = b1[c];
    w2v[ct] = W2[c];
  }
  const float b2s = b2p[0];

  int ti = blockIdx.x;
  int4 M = meta[ti];

  // prologue: stage first tile into buf[0]
  {
    const int node0 = ti * 32;
    #pragma unroll
    for (int i = 0; i < 8; ++i) {
      const int r = i * 4 + w;
      int grow = node0 + r;
      if (grow >= N) grow = N - 1;
      dma16(x + (size_t)grow * 256 + ((l ^ (r & 7)) << 2), buf[0] + r * 1024);
    }
  }
  asm volatile("s_waitcnt vmcnt(0)" ::: "memory");
  __builtin_amdgcn_s_barrier();
  __builtin_amdgcn_sched_barrier(0);

  int par = 0;
  for (; ti < ntiles; ti += PBLOCKS) {
    const int tnext = ti + PBLOCKS;
    int4 Mnext = M;
    if (tnext < ntiles) {
      Mnext = meta[tnext];                       // older than the DMAs below:
      const int nn0 = tnext * 32;                // its wait won't drain them
      char* dst = buf[par ^ 1];
      #pragma unroll
      for (int i = 0; i < 8; ++i) {
        const int r = i * 4 + w;
        int grow = nn0 + r;
        if (grow >= N) grow = N - 1;
        dma16(x + (size_t)grow * 256 + ((l ^ (r & 7)) << 2), dst + r * 1024);
      }
    }
    __builtin_amdgcn_sched_barrier(0);

    const char* tile = buf[par];
    const int node0 = ti * 32;

    // ---- Phase A: MFMA scores; pair wp owns rows wp*16..+15 (LDS+regs) ----
    {
      const int r0 = wp * 16 + l15;
      const char* p0 = tile + r0 * 1024;
      const int s0 = (r0 & 7);
      f32x4 acc0 = {0.f,0.f,0.f,0.f}, acc1 = {0.f,0.f,0.f,0.f};
      f32x4 acc2 = {0.f,0.f,0.f,0.f}, acc3 = {0.f,0.f,0.f,0.f};
      #pragma unroll
      for (int kt = 0; kt < 8; ++kt) {
        const int cc = kt * 8 + lg * 2;
        float4 xa = *(const float4*)(p0 + (((cc    ) ^ s0) << 4));
        float4 xb = *(const float4*)(p0 + (((cc + 1) ^ s0) << 4));
        s16x8 a;
        a[0] = f2bf(xa.x); a[1] = f2bf(xa.y); a[2] = f2bf(xa.z); a[3] = f2bf(xa.w);
        a[4] = f2bf(xb.x); a[5] = f2bf(xb.y); a[6] = f2bf(xb.z); a[7] = f2bf(xb.w);
        acc0 = __builtin_amdgcn_mfma_f32_16x16x32_bf16(a, bf[0][kt], acc0, 0, 0, 0);
        acc1 = __builtin_amdgcn_mfma_f32_16x16x32_bf16(a, bf[1][kt], acc1, 0, 0, 0);
        acc2 = __builtin_amdgcn_mfma_f32_16x16x32_bf16(a, bf[2][kt], acc2, 0, 0, 0);
        acc3 = __builtin_amdgcn_mfma_f32_16x16x32_bf16(a, bf[3][kt], acc3, 0, 0, 0);
      }
      // h = tanh(acc+b1); partial score over this wave's 64 cols.
      // D layout: node-in-tile = 4*lg + r, hidden-col = ct*16 + l15.
      float part[4];
      #pragma unroll
      for (int r = 0; r < 4; ++r) {
        part[r] = colhalf ? 0.f : b2s;
        part[r] += fast_tanh(acc0[r] + b1v[0]) * w2v[0];
        part[r] += fast_tanh(acc1[r] + b1v[1]) * w2v[1];
        part[r] += fast_tanh(acc2[r] + b1v[2]) * w2v[2];
        part[r] += fast_tanh(acc3[r] + b1v[3]) * w2v[3];
      }
      #pragma unroll
      for (int m = 1; m <= 8; m <<= 1) {
        #pragma unroll
        for (int r = 0; r < 4; ++r) part[r] += __shfl_xor(part[r], m, 64);
      }
      if (l15 == 0) {
        #pragma unroll
        for (int r = 0; r < 4; ++r)
          sp[colhalf][wp * 16 + lg * 4 + r] = part[r];
      }
    }
    asm volatile("s_waitcnt lgkmcnt(0)" ::: "memory");
    __builtin_amdgcn_s_barrier();
    __builtin_amdgcn_sched_barrier(0);

    // combine halves, exponentiate (no max: |score| <= ~9), store
    if (tid < 32) {
      int node = node0 + tid;
      float e = 0.f;
      if (node < N) {
        e = __expf(sp[0][tid] + sp[1][tid]);
        expout[node] = e;
      }
      sw[tid] = e;
    }
    asm volatile("s_waitcnt lgkmcnt(0)" ::: "memory");
    __builtin_amdgcn_s_barrier();
    __builtin_amdgcn_sched_barrier(0);

    // ---- Phase B: pooling from LDS, col = tid; meta-resident offs ----
    {
      const int nmax = min(32, N - node0);
      int g = M.x;
      int nb = M.y;
      int crossing = 0;
      const int ccb = tid >> 2, cib = (tid & 3) << 2;
      int r = 0;
      while (r < nmax) {
        const int rend = min(nb - node0, nmax);
        float pacc = 0.f, wsum = 0.f;
        for (; r + 8 <= rend; r += 8) {
          float xv[8], wv[8];
          #pragma unroll
          for (int u = 0; u < 8; ++u) {
            const int rr = r + u;
            xv[u] = *(const float*)(tile + rr * 1024 + (((ccb ^ (rr & 7)) << 4) | cib));
            wv[u] = sw[rr];
          }
          #pragma unroll
          for (int u = 0; u < 8; ++u) {
            pacc += wv[u] * xv[u];
            wsum += wv[u];
          }
        }
        for (; r < rend; ++r) {
          float wv = sw[r];
          pacc += wv * *(const float*)(tile + r * 1024 + (((ccb ^ (r & 7)) << 4) | cib));
          wsum += wv;
        }
        if (wsum > 0.f) {
          atomicAdd(&pooled[(size_t)g * 256 + tid], pacc);
          if (tid == 0) atomicAdd(&segsum[g], wsum);
        }
        if (rend >= nmax) break;
        ++g; ++crossing;
        nb = (crossing == 1) ? M.z
           : (crossing == 2) ? M.w
           : offs[min(g + 1, NGRAPH)];   // lazy fallback (rare)
      }
    }

    asm volatile("s_waitcnt vmcnt(0)" ::: "memory");  // residual prefetch drain
    __builtin_amdgcn_s_barrier();
    __builtin_amdgcn_sched_barrier(0);
    M = Mnext;
    par ^= 1;
  }
}

// Finalize: pooled /= segsum (0 for empty graphs), weights = exp/segsum[batch].
__global__ void finalize(float* __restrict__ pooled, float* __restrict__ wts,
                         const float* __restrict__ segsum,
                         const void* __restrict__ batch, int N)
{
  int f = blockIdx.x * 256 + threadIdx.x;
  if (f < NGRAPH * 256) {
    int g = f >> 8;
    float s = segsum[g];
    pooled[f] = (s > 0.f) ? pooled[f] / s : 0.f;
  } else {
    int n = f - NGRAPH * 256;
    if (n < N) {
      const int is64 = batch_is64(batch, N);
      int g = (int)getb(batch, n, is64);
      wts[n] = wts[n] / segsum[g];
    }
  }
}

extern "C" void kernel_launch(void* const* d_in, const int* in_sizes, int n_in,
                              void* d_out, int out_size, void* d_ws, size_t ws_size,
                              hipStream_t stream) {
  const float* x     = (const float*)d_in[0];
  const void*  batch = d_in[1];
  const float* W1    = (const float*)d_in[2];
  const float* b1    = (const float*)d_in[3];
  const float* W2    = (const float*)d_in[4];
  const float* b2    = (const float*)d_in[5];
  const int N = in_sizes[0] / 256;
  const int ntiles = (N + 31) / 32;

  float* pooled = (float*)d_out;                          // 4096*256
  float* wout   = (float*)d_out + (size_t)NGRAPH * 256;   // N: exp(s), then weights
  s16x8* w1p    = (s16x8*)d_ws;                           // 64 KB
  int*   offs   = (int*)((char*)d_ws + 64 * 1024);        // 4097 * 4 B
  float* segsum = (float*)((char*)d_ws + 96 * 1024);      // 4096 * 4 B
  int4*  meta   = (int4*)((char*)d_ws + 128 * 1024);      // ntiles * 16 B (~250 KB)

  const int metaB = (ntiles + 255) / 256;
  const int zeroB = 64;
  const int setupB = 33 + metaB + zeroB;

  setup<<<setupB, 256, 0, stream>>>(W1, batch, w1p, offs, meta,
                                    pooled, segsum, N, ntiles, metaB, zeroB);
  gate_pool<<<PBLOCKS, 256, 0, stream>>>(x, meta, offs, b1, W2, b2, w1p,
                                         pooled, wout, segsum, N, ntiles);
  const int tot = NGRAPH * 256 + N;
  finalize<<<(tot + 255) / 256, 256, 0, stream>>>(pooled, wout, segsum, batch, N);
}